// Round 19
// baseline (375.580 us; speedup 1.0000x reference)
//
#include <hip/hip_runtime.h>

static constexpr int NB = 2048;
static constexpr float SENT = -1e30f;

typedef __attribute__((ext_vector_type(8))) short bf16x8;
typedef __attribute__((ext_vector_type(4))) float f32x4;

// rotated-3x3 tap permutation: weight tap k of rotation r lands at patch position DST[r][k]
static constexpr int DST[8][9] = {
  {8,7,6,5,4,3,2,1,0},
  {5,8,7,2,4,6,1,0,3},
  {2,5,8,1,4,7,0,3,6},
  {1,2,5,0,4,8,3,6,7},
  {0,1,2,3,4,5,6,7,8},
  {3,0,1,6,4,2,7,8,5},
  {6,3,0,7,4,1,8,5,2},
  {7,6,3,8,4,0,5,2,1},
};

__device__ __forceinline__ unsigned short f2bf(float f){
  unsigned int u = __float_as_uint(f);
  u += 0x7fffu + ((u>>16)&1u);          // RNE
  return (unsigned short)(u>>16);
}
__device__ __forceinline__ float bf2f(unsigned short s){
  return __uint_as_float((unsigned int)s << 16);
}

// border cell index (16x16 plane) for border id t<60
__device__ __forceinline__ int border_cell(int t){
  if (t<16) return t;
  if (t<32) return 240 + (t-16);
  if (t<46) return (t-31)*16;
  return (t-45)*16 + 15;
}

// ---------------- init: zero stats + bf16 weight packs for conv2/3/4/5/6 MFMA ----------------
__global__ __launch_bounds__(256) void k_init(const float* __restrict__ w2, const float* __restrict__ w3,
                                              const float* __restrict__ w4,
                                              const float* __restrict__ w5, const float* __restrict__ w6,
                                              unsigned short* __restrict__ B2,
                                              unsigned short* __restrict__ B3,
                                              unsigned short* __restrict__ wb4,
                                              unsigned short* __restrict__ wb5, unsigned short* __restrict__ wb6,
                                              float* __restrict__ st){
  int i = blockIdx.x*256 + threadIdx.x;
  if (i < 2048) st[i] = 0.f;
  if (i < 18432){                                  // 9*64*32
    int tap = i/2048, rem = i%2048, oc = rem/32, ci = rem%32;
    wb5[i] = f2bf(w5[(oc*32+ci)*9 + tap]);
  } else if (i < 55296){                           // + 9*64*64
    int j = i - 18432;
    int tap = j/4096, rem = j%4096, oc = rem/64, ci = rem%64;
    wb6[j] = f2bf(w6[(oc*64+ci)*9 + tap]);
  } else if (i < 64512){                           // + 9*32*32
    int j = i - 55296;
    int tap = j/1024, rem = j%1024, oc = rem/32, ci = rem%32;
    wb4[j] = f2bf(w4[(oc*32+ci)*9 + tap]);
  } else if (i < 67072){                           // + conv2 tap-pair pack [5][16][32]
    int j = i - 64512;
    int c = j >> 9;
    int rem = j & 511;
    int o = rem >> 5, k = rem & 31;
    int tap = c*2 + (k>>4);
    int ci = k & 15;
    unsigned short v = 0;
    if (tap <= 8){
      int rot = o>>1, u = o&1;
      int bb = ci>>1, ui = ci&1;
      int wc = (((bb - rot) & 7)<<1) | ui;
      int kk = 0;
      #pragma unroll
      for (int q=0;q<9;q++) if (DST[rot][q]==tap) kk=q;
      v = f2bf(w2[(u*16+wc)*9 + kk]);
    }
    B2[j] = v;
  } else if (i < 72192){                           // + conv3 tap-pair pack [5][32][32]
    int j = i - 67072;
    int c = j >> 10;
    int rem = j & 1023;
    int o = rem >> 5, k = rem & 31;
    int tap = c*2 + (k>>4);
    int ci = k & 15;
    unsigned short v = 0;
    if (tap <= 8){
      int rot = o>>2, uh = (o>>1)&1, ul = o&1;
      int bb = ci>>1, ui = ci&1;
      int wc = (((bb - rot) & 7)<<1) | ui;
      int kk = 0;
      #pragma unroll
      for (int q=0;q<9;q++) if (DST[rot][q]==tap) kk=q;
      v = f2bf(w3[uh*288 + (ul*16+wc)*9 + kk]);
    }
    B3[j] = v;
  }
}

// ---------------- init7: conv7-as-GEMM B matrix [n=256][k=1024] bf16 ----------------
__global__ __launch_bounds__(256) void k_init7(const float* __restrict__ w7,
                                               unsigned short* __restrict__ Bl){
  int i = blockIdx.x*256 + threadIdx.x;            // 262144 exact (1024 blocks)
  int n = i>>10, k = i&1023;
  int pos16 = k>>6, ci = k&63;
  int r = pos16>>2, c = pos16&3;
  unsigned short v = 0;
  if (n < 250){
    int pos = n/10, o = n - 10*(n/10);
    int py = pos/5, px = pos - 5*(pos/5);
    int ky = r - py + 2, kx = c - px + 2;
    if (ky>=0 && ky<4 && kx>=0 && kx<4) v = f2bf(w7[(o*64+ci)*16 + ky*4 + kx]);
  }
  Bl[i] = v;
}

// ---------------- stats of y1 = rotconv1(x), y1 never materialized ----------------
__global__ __launch_bounds__(256) void k_stats1(const float* __restrict__ x,
                                                const float* __restrict__ w1,
                                                float* __restrict__ st){
  __shared__ float wp[192];
  __shared__ float red[4][32];
  for (int i=threadIdx.x; i<144; i+=256){
    int rot = i/18, rem = i-rot*18, u = rem/9, k = rem-u*9;
    wp[(rot*2+u)*12 + DST[rot][k]] = w1[u*9+k];
  }
  __syncthreads();
  float s[16], s2[16];
  #pragma unroll
  for (int o=0;o<16;o++){ s[o]=0.f; s2[o]=0.f; }
  for (int idx = blockIdx.x*256 + threadIdx.x; idx < NB*784; idx += 512*256){
    int b = idx/784, pix = idx-b*784;
    int py = pix/28, px = pix-py*28;
    const float* xb = x + (size_t)b*784;
    float tap[9];
    #pragma unroll
    for (int d=0; d<9; d++){
      int dy = d/3-1, dx = d%3-1;
      int yy = py+dy, xx = px+dx;
      tap[d] = (yy>=0 && yy<28 && xx>=0 && xx<28) ? xb[yy*28+xx] : 0.f;
    }
    #pragma unroll
    for (int ci=0; ci<16; ci++){
      float y = 0.f;
      #pragma unroll
      for (int d=0; d<9; d++) y += wp[ci*12+d]*tap[d];
      s[ci] += y; s2[ci] += y*y;
    }
  }
  int wid = threadIdx.x>>6;
  #pragma unroll
  for (int o=0;o<16;o++){
    float a = s[o], b2 = s2[o];
    #pragma unroll
    for (int off=32; off; off>>=1){ a += __shfl_down(a,off); b2 += __shfl_down(b2,off); }
    if ((threadIdx.x&63)==0){ red[wid][o] = a; red[wid][16+o] = b2; }
  }
  __syncthreads();
  if (threadIdx.x < 32){
    float v = red[0][threadIdx.x]+red[1][threadIdx.x]+red[2][threadIdx.x]+red[3][threadIdx.x];
    int c = threadIdx.x & 15;
    atomicAdd(&st[(threadIdx.x<16)? c : 64+c], v);
  }
}

// ---------------- conv2 MFMA: recompute y1 from x in-block; bn1 coef in-block; bf16 out-buffer ----------------
// LDS union: staging {Ls bf16[960][16]=7680fl | xs 960 | wp 192} = 8832fl ; out16 bf16 [784][17] = 6664fl.
__global__ __launch_bounds__(256, 2) void k_conv2m(const float* __restrict__ x,
                                                   const float* __restrict__ w1,
                                                   const unsigned short* __restrict__ B2,  // [5][16][32] bf16
                                                   const float* __restrict__ stin,   // bn1 sums
                                                   const float* __restrict__ g1, const float* __restrict__ b1,
                                                   float* __restrict__ p2p,
                                                   float* __restrict__ st){
  __shared__ float smemf[8832];
  __shared__ float ca[16], cb[16];
  __shared__ float red[4][32];
  unsigned short* Ls = (unsigned short*)smemf;   // floats [0, 7680)
  float* xs = smemf + 7680;                      // floats [7680, 8640)
  float* wp = smemf + 8640;                      // floats [8640, 8832)
  unsigned short* out16 = (unsigned short*)smemf;  // [784][17] shorts = 6664 fl
  int t = threadIdx.x;
  int wid = t>>6, lane = t&63;
  int quad = lane>>4, m = lane&15;
  for (int i=t; i<144; i+=256){
    int rot = i/18, rem = i-rot*18, u = rem/9, k = rem-u*9;
    wp[(rot*2+u)*12 + DST[rot][k]] = w1[u*9+k];
  }
  if (t < 16){
    const float invN = 1.f/1605632.f;
    float mu = stin[t]*invN;
    float var = stin[64+t]*invN - mu*mu;
    float a = g1[t&1]*rsqrtf(var + 1e-5f);
    ca[t] = a; cb[t] = b1[t&1] - mu*a;
  }
  int b = blockIdx.x;
  for (int i=t; i<960; i+=256){
    int r = i>>5, c = i&31;
    int iy = r-1, ix = c-1;
    xs[i] = (iy>=0 && iy<28 && ix>=0 && ix<28) ? x[(size_t)b*784 + iy*28 + ix] : 0.f;
  }
  for (int i=t; i<3840; i+=256) ((unsigned long long*)Ls)[i] = 0ULL;
  __syncthreads();
  for (int i=t; i<784; i+=256){
    int py = i/28, px = i - 28*(i/28);
    float tap[9];
    #pragma unroll
    for (int d=0; d<9; d++) tap[d] = xs[(py + d/3)*32 + px + d%3];
    unsigned long long pk[4];
    #pragma unroll
    for (int q=0; q<4; q++){
      unsigned long long p = 0;
      #pragma unroll
      for (int j=0; j<4; j++){
        int ci = q*4 + j;
        float y = 0.f;
        #pragma unroll
        for (int d=0; d<9; d++) y += wp[ci*12+d]*tap[d];
        float rv = fmaxf(y*ca[ci] + cb[ci], 0.f);
        p |= ((unsigned long long)f2bf(rv)) << (16*j);
      }
      pk[q] = p;
    }
    int cell = (py+1)*32 + px + 1;
    unsigned long long* dstp = (unsigned long long*)(Ls + cell*16);
    dstp[0]=pk[0]; dstp[1]=pk[1]; dstp[2]=pk[2]; dstp[3]=pk[3];
  }
  __syncthreads();
  f32x4 acc[13];
  #pragma unroll
  for (int j=0;j<13;j++) acc[j] = (f32x4){0.f,0.f,0.f,0.f};
  #pragma unroll
  for (int c=0;c<5;c++){
    int tapA = 2*c, tapB = (2*c+1 < 9) ? 2*c+1 : 8;
    int dyA = tapA/3, dxA = tapA - 3*(tapA/3);
    int dyB = tapB/3, dxB = tapB - 3*(tapB/3);
    bf16x8 Bf = *(const bf16x8*)(B2 + (c*16 + m)*32 + quad*8);
    #pragma unroll
    for (int j=0;j<13;j++){
      int mt = wid + 4*j;
      if (mt >= 49) continue;
      int pos = mt*16 + m;
      int py = pos/28, px = pos - py*28;
      int pix = (quad < 2) ? ((py+dyA)*32 + px+dxA) : ((py+dyB)*32 + px+dxB);
      bf16x8 Af = *(const bf16x8*)(Ls + pix*16 + (quad&1)*8);
      acc[j] = __builtin_amdgcn_mfma_f32_16x16x32_bf16(Af, Bf, acc[j], 0, 0, 0);
    }
  }
  __syncthreads();
  float s = 0.f, sq = 0.f;
  #pragma unroll
  for (int j=0;j<13;j++){
    int mt = wid + 4*j;
    if (mt >= 49) continue;
    #pragma unroll
    for (int r=0;r<4;r++){
      int pos = mt*16 + quad*4 + r;
      float v = acc[j][r];
      out16[pos*17 + m] = f2bf(v);
      s += v; sq += v*v;
    }
  }
  s += __shfl_down(s,32);  s += __shfl_down(s,16);
  sq += __shfl_down(sq,32); sq += __shfl_down(sq,16);
  if (lane < 16){ red[wid][m] = s; red[wid][16+m] = sq; }
  __syncthreads();
  if (t < 32){
    float v = red[0][t]+red[1][t]+red[2][t]+red[3][t];
    int c = t & 15;
    atomicAdd(&st[(t<16)? c : 64+c], v);
  }
  for (int i=t; i<3136; i+=256){
    int cell = i>>4, oc = i&15;
    int yo = cell/14, xo = cell - yo*14;
    const unsigned short* o00 = out16 + ((yo*2)*28 + xo*2)*17 + oc;
    float mx = fmaxf(fmaxf(bf2f(o00[0]), bf2f(o00[17])), fmaxf(bf2f(o00[476]), bf2f(o00[493])));
    p2p[((size_t)b*16+oc)*256 + (yo+1)*16 + xo + 1] = mx;
  }
  for (int i=t; i<960; i+=256){
    int bc = border_cell(i>>4), oc = i&15;
    p2p[((size_t)b*16+oc)*256 + bc] = SENT;
  }
}

// ---------------- conv3 MFMA: 16->32 rotated over 14x14, bn2 coef in-block, bf16 out-buffer ----------------
// LDS union: staging Ls bf16[256][16] = 2048fl ; out16 bf16 [196][33] = 3234fl -> smemf[3234].
__global__ __launch_bounds__(256, 2) void k_conv3m(const float* __restrict__ p2p,
                                                   const unsigned short* __restrict__ B3,  // [5][32][32] bf16
                                                   const float* __restrict__ stin,
                                                   const float* __restrict__ g2, const float* __restrict__ b2,
                                                   float* __restrict__ y3p,
                                                   float* __restrict__ st){
  __shared__ float smemf[3234];
  __shared__ float ca[16], cb[16];
  __shared__ float red[4][64];
  unsigned short* Ls = (unsigned short*)smemf;
  unsigned short* out16 = (unsigned short*)smemf;   // [196][33]
  int t = threadIdx.x;
  int wid = t>>6, lane = t&63;
  int quad = lane>>4, m = lane&15;
  if (t < 16){
    const float invN = 1.f/1605632.f;
    float mu = stin[t]*invN;
    float var = stin[64+t]*invN - mu*mu;
    float a = g2[t&1]*rsqrtf(var + 1e-5f);
    ca[t] = a; cb[t] = b2[t&1] - mu*a;
  }
  __syncthreads();
  int b = blockIdx.x;
  const float* sb = p2p + (size_t)b*4096;
  #pragma unroll
  for (int it=0; it<4; it++){
    unsigned long long pk = 0;
    #pragma unroll
    for (int j=0;j<4;j++){
      int ci = it*4 + j;
      float v = fmaxf(sb[ci*256 + t]*ca[ci] + cb[ci], 0.f);
      pk |= ((unsigned long long)f2bf(v)) << (16*j);
    }
    *(unsigned long long*)(Ls + t*16 + it*4) = pk;
  }
  __syncthreads();
  int py[4], px[4]; bool vt[4];
  #pragma unroll
  for (int j=0;j<4;j++){
    int mt = wid + 4*j;
    int pos = mt*16 + m;
    vt[j] = (mt <= 12);
    if (pos >= 196) pos = 0;
    py[j] = pos/14; px[j] = pos%14;
  }
  f32x4 acc[4][2];
  #pragma unroll
  for (int j=0;j<4;j++){ acc[j][0] = (f32x4){0,0,0,0}; acc[j][1] = (f32x4){0,0,0,0}; }
  #pragma unroll
  for (int c=0;c<5;c++){
    int tapA = 2*c, tapB = (2*c+1 < 9) ? 2*c+1 : 8;
    int dyA = tapA/3, dxA = tapA - 3*(tapA/3);
    int dyB = tapB/3, dxB = tapB - 3*(tapB/3);
    bf16x8 Bf[2];
    #pragma unroll
    for (int nt=0; nt<2; nt++)
      Bf[nt] = *(const bf16x8*)(B3 + (c*32 + nt*16 + m)*32 + quad*8);
    bf16x8 Af[4];
    #pragma unroll
    for (int j=0;j<4;j++){
      int pix = (quad < 2) ? ((py[j]+dyA)*16 + px[j]+dxA) : ((py[j]+dyB)*16 + px[j]+dxB);
      Af[j] = *(const bf16x8*)(Ls + pix*16 + (quad&1)*8);
    }
    #pragma unroll
    for (int j=0;j<4;j++){
      if (!vt[j]) continue;
      acc[j][0] = __builtin_amdgcn_mfma_f32_16x16x32_bf16(Af[j], Bf[0], acc[j][0], 0, 0, 0);
      acc[j][1] = __builtin_amdgcn_mfma_f32_16x16x32_bf16(Af[j], Bf[1], acc[j][1], 0, 0, 0);
    }
  }
  __syncthreads();   // done reading Ls; reuse as out16
  float s0=0.f,sq0=0.f,s1=0.f,sq1=0.f;
  #pragma unroll
  for (int j=0;j<4;j++){
    if (!vt[j]) continue;
    int mt = wid + 4*j;
    #pragma unroll
    for (int r=0;r<4;r++){
      int pos = mt*16 + quad*4 + r;
      if (pos < 196){
        float v0 = acc[j][0][r], v1 = acc[j][1][r];
        out16[pos*33 + m]      = f2bf(v0);
        out16[pos*33 + 16 + m] = f2bf(v1);
        s0 += v0; sq0 += v0*v0; s1 += v1; sq1 += v1*v1;
      }
    }
  }
  s0 += __shfl_down(s0,32); s0 += __shfl_down(s0,16);
  sq0 += __shfl_down(sq0,32); sq0 += __shfl_down(sq0,16);
  s1 += __shfl_down(s1,32); s1 += __shfl_down(s1,16);
  sq1 += __shfl_down(sq1,32); sq1 += __shfl_down(sq1,16);
  if (lane < 16){
    red[wid][m]      = s0;  red[wid][32+m]      = sq0;
    red[wid][16+m]   = s1;  red[wid][32+16+m]   = sq1;
  }
  __syncthreads();
  if (t < 64){
    float v = red[0][t]+red[1][t]+red[2][t]+red[3][t];
    int c = t & 31;
    atomicAdd(&st[(t<32)? c : 64+c], v);
  }
  for (int i=t; i<6272; i+=256){
    int oc = i/196, pos = i - oc*196;
    int py2 = pos/14, px2 = pos - py2*14;
    y3p[(size_t)b*8192 + oc*256 + (py2+1)*16 + px2 + 1] = bf2f(out16[pos*33 + oc]);
  }
  for (int i=t; i<1920; i+=256){
    int bc = border_cell(i>>5), oc = i&31;
    y3p[(size_t)b*8192 + oc*256 + bc] = SENT;
  }
}

// ---------------- conv4 MFMA: 32->32 over 14x14, bn3 coef in-block, FUSED NMS, bf16 out-buffer ----------------
// LDS union: staging L bf16[256][40] = 5120fl ; out16 [196][33] = 3234fl -> smemf[5120].
__global__ __launch_bounds__(256, 2) void k_conv4m(const float* __restrict__ y3p,
                                                   const unsigned short* __restrict__ wb4, // [9][32][32] bf16
                                                   const float* __restrict__ stin,
                                                   const float* __restrict__ g3, const float* __restrict__ b3,
                                                   float* __restrict__ p4,
                                                   float* __restrict__ st,
                                                   float* __restrict__ nmsa){
  __shared__ float smemf[5120];
  __shared__ float ca[32], cb[32];
  __shared__ float red[4][64];
  __shared__ float nred[4];
  unsigned short* L = (unsigned short*)smemf;
  unsigned short* out16 = (unsigned short*)smemf;   // [196][33]
  int t = threadIdx.x;
  int wid = t>>6, lane = t&63;
  int quad = lane>>4, m = lane&15;
  if (t < 32){
    const float invN = 1.f/401408.f;
    float mu = stin[t]*invN;
    float var = stin[64+t]*invN - mu*mu;
    float a = g3[t&3]*rsqrtf(var + 1e-5f);
    ca[t] = a; cb[t] = b3[t&3] - mu*a;
  }
  __syncthreads();
  int b = blockIdx.x;
  const float* sb = y3p + (size_t)b*8192;
  #pragma unroll
  for (int it=0; it<8; it++){
    int cell = t;
    unsigned long long pk = 0;
    #pragma unroll
    for (int j=0;j<4;j++){
      int ci = it*4 + j;
      float v = fmaxf(sb[ci*256 + cell]*ca[ci] + cb[ci], 0.f);
      pk |= ((unsigned long long)f2bf(v)) << (16*j);
    }
    *(unsigned long long*)(L + cell*40 + it*4) = pk;
  }
  __syncthreads();
  float nloc = 0.f;
  for (int i=t; i<784; i+=256){
    int hw = i>>2, c4 = i&3;
    int cell = (hw/14 + 1)*16 + hw%14 + 1;
    const unsigned short* g = L + cell*40 + c4*8;
    float v[8]; float vmax = -1e30f;
    #pragma unroll
    for (int r=0;r<8;r++){
      v[r] = bf2f(g[r]);
      vmax = fmaxf(vmax, v[r]);
    }
    #pragma unroll
    for (int r=0;r<8;r++) nloc += (v[r] != vmax) ? v[r] : 0.f;
  }
  #pragma unroll
  for (int off=32; off; off>>=1) nloc += __shfl_down(nloc, off);
  if (lane == 0) nred[wid] = nloc;
  int py[4], px[4]; bool vt[4];
  #pragma unroll
  for (int j=0;j<4;j++){
    int mt = wid + 4*j;
    int pos = mt*16 + m;
    vt[j] = (mt <= 12);
    if (pos >= 196) pos = 0;
    py[j] = pos/14; px[j] = pos%14;
  }
  f32x4 acc[4][2];
  #pragma unroll
  for (int j=0;j<4;j++){ acc[j][0] = (f32x4){0,0,0,0}; acc[j][1] = (f32x4){0,0,0,0}; }
  for (int tap=0; tap<9; tap++){
    int dy = tap/3, dx = tap - dy*3;
    bf16x8 Bf[2];
    #pragma unroll
    for (int nt=0; nt<2; nt++)
      Bf[nt] = *(const bf16x8*)(wb4 + (tap*32 + nt*16 + m)*32 + quad*8);
    bf16x8 Af[4];
    #pragma unroll
    for (int j=0;j<4;j++)
      Af[j] = *(const bf16x8*)(L + ((py[j]+dy)*16 + px[j]+dx)*40 + quad*8);
    #pragma unroll
    for (int j=0;j<4;j++){
      if (!vt[j]) continue;
      acc[j][0] = __builtin_amdgcn_mfma_f32_16x16x32_bf16(Af[j], Bf[0], acc[j][0], 0, 0, 0);
      acc[j][1] = __builtin_amdgcn_mfma_f32_16x16x32_bf16(Af[j], Bf[1], acc[j][1], 0, 0, 0);
    }
  }
  __syncthreads();
  if (t == 0) atomicAdd(nmsa, nred[0]+nred[1]+nred[2]+nred[3]);
  float s0=0.f,sq0=0.f,s1=0.f,sq1=0.f;
  #pragma unroll
  for (int j=0;j<4;j++){
    if (!vt[j]) continue;
    int mt = wid + 4*j;
    #pragma unroll
    for (int r=0;r<4;r++){
      int pos = mt*16 + quad*4 + r;
      if (pos < 196){
        float v0 = acc[j][0][r], v1 = acc[j][1][r];
        out16[pos*33 + m]      = f2bf(v0);
        out16[pos*33 + 16 + m] = f2bf(v1);
        s0 += v0; sq0 += v0*v0; s1 += v1; sq1 += v1*v1;
      }
    }
  }
  s0 += __shfl_down(s0,32); s0 += __shfl_down(s0,16);
  sq0 += __shfl_down(sq0,32); sq0 += __shfl_down(sq0,16);
  s1 += __shfl_down(s1,32); s1 += __shfl_down(s1,16);
  sq1 += __shfl_down(sq1,32); sq1 += __shfl_down(sq1,16);
  if (lane < 16){
    red[wid][m]      = s0;  red[wid][32+m]      = sq0;
    red[wid][16+m]   = s1;  red[wid][32+16+m]   = sq1;
  }
  __syncthreads();
  if (t < 64){
    float v = red[0][t]+red[1][t]+red[2][t]+red[3][t];
    int c = t & 31;
    atomicAdd(&st[(t<32)? c : 64+c], v);
  }
  for (int i=t; i<1568; i+=256){
    int cell = i>>5, oc = i&31;
    int yo = cell/7, xo = cell - yo*7;
    const unsigned short* o00 = out16 + ((yo*2)*14 + xo*2)*33 + oc;
    float mx = fmaxf(fmaxf(bf2f(o00[0]), bf2f(o00[33])), fmaxf(bf2f(o00[14*33]), bf2f(o00[15*33])));
    p4[((size_t)b*49 + cell)*32 + oc] = mx;
  }
}

// ---------------- conv5/conv6 MFMA: CI->64, per-wave batch, bn coef in-block, shift-GEMM over 9 taps ----------------
template<int CI>
__global__ __launch_bounds__(256, 2) void k_conv56m(const float* __restrict__ src,
                                                    const unsigned short* __restrict__ wb,  // [9][64][CI] bf16
                                                    const float* __restrict__ stin,
                                                    const float* __restrict__ g, const float* __restrict__ be,
                                                    float invN,
                                                    float* __restrict__ dst,
                                                    float* __restrict__ st){
  constexpr int CIP = CI + 8;
  constexpr int KC = CI/32;
  __shared__ unsigned short lin[4][81*CIP];
  __shared__ float red[4][256];
  __shared__ float ca[CI], cb[CI];
  int wid = threadIdx.x>>6, lane = threadIdx.x&63;
  int quad = lane>>4, m = lane&15;
  unsigned short* L = lin[wid];
  if (threadIdx.x < CI){
    int i = threadIdx.x;
    float mu = stin[i]*invN;
    float var = stin[64+i]*invN - mu*mu;
    float a = g[i]*rsqrtf(var + 1e-5f);
    ca[i] = a; cb[i] = be[i] - mu*a;
  }
  for (int i = lane; i < 81*CIP/4; i += 64) ((unsigned long long*)L)[i] = 0ULL;
  __syncthreads();
  int b = blockIdx.x*4 + wid;
  const float* sb = src + (size_t)b*49*CI;
  for (int i = lane; i < 49*CI/4; i += 64){
    int pos = i/(CI/4), cig = i - pos*(CI/4);
    float4 v = *(const float4*)(sb + pos*CI + cig*4);
    float r0 = fmaxf(v.x*ca[cig*4]  +cb[cig*4],   0.f);
    float r1 = fmaxf(v.y*ca[cig*4+1]+cb[cig*4+1], 0.f);
    float r2 = fmaxf(v.z*ca[cig*4+2]+cb[cig*4+2], 0.f);
    float r3 = fmaxf(v.w*ca[cig*4+3]+cb[cig*4+3], 0.f);
    int pos9 = (pos/7 + 1)*9 + pos%7 + 1;
    unsigned long long pk = (unsigned long long)f2bf(r0)
                          | ((unsigned long long)f2bf(r1)<<16)
                          | ((unsigned long long)f2bf(r2)<<32)
                          | ((unsigned long long)f2bf(r3)<<48);
    *(unsigned long long*)(L + pos9*CIP + cig*4) = pk;
  }
  __syncthreads();
  int py[4], px[4];
  #pragma unroll
  for (int mt=0; mt<4; mt++){
    int pos = mt*16 + m;
    if (pos < 49){ py[mt] = pos/7; px[mt] = pos%7; }
    else { py[mt] = 0; px[mt] = 0; }
  }
  f32x4 acc[4][4];
  #pragma unroll
  for (int nt=0; nt<4; nt++)
    #pragma unroll
    for (int mt=0; mt<4; mt++) acc[nt][mt] = (f32x4){0.f,0.f,0.f,0.f};

  for (int tap=0; tap<9; tap++){
    int dy = tap/3, dx = tap - dy*3;
    int o9[4];
    #pragma unroll
    for (int mt=0; mt<4; mt++) o9[mt] = ((py[mt]+dy)*9 + px[mt]+dx)*CIP;
    #pragma unroll
    for (int kc=0; kc<KC; kc++){
      int ko = kc*32 + quad*8;
      bf16x8 Bf[4], Af[4];
      #pragma unroll
      for (int nt=0; nt<4; nt++)
        Bf[nt] = *(const bf16x8*)(wb + (tap*64 + nt*16 + m)*CI + ko);
      #pragma unroll
      for (int mt=0; mt<4; mt++)
        Af[mt] = *(const bf16x8*)(L + o9[mt] + ko);
      #pragma unroll
      for (int nt=0; nt<4; nt++)
        #pragma unroll
        for (int mt=0; mt<4; mt++)
          acc[nt][mt] = __builtin_amdgcn_mfma_f32_16x16x32_bf16(Af[mt], Bf[nt], acc[nt][mt], 0, 0, 0);
    }
  }
  float* db = dst + (size_t)b*49*64;
  float snt[4], sqnt[4];
  #pragma unroll
  for (int nt=0; nt<4; nt++){
    float s = 0.f, sq = 0.f;
    #pragma unroll
    for (int mt=0; mt<4; mt++){
      #pragma unroll
      for (int r=0; r<4; r++){
        int pos = mt*16 + quad*4 + r;
        if (pos < 49){
          float v = acc[nt][mt][r];
          db[pos*64 + nt*16 + m] = v;
          s += v; sq += v*v;
        }
      }
    }
    s += __shfl_down(s, 32);  s += __shfl_down(s, 16);
    sq += __shfl_down(sq, 32); sq += __shfl_down(sq, 16);
    snt[nt] = s; sqnt[nt] = sq;
  }
  if (lane < 16){
    #pragma unroll
    for (int nt=0; nt<4; nt++){
      red[wid][nt*16 + lane] = snt[nt];
      red[wid][128 + nt*16 + lane] = sqnt[nt];
    }
  }
  __syncthreads();
  if (threadIdx.x < 128){
    int c = threadIdx.x & 63;
    int off = (threadIdx.x < 64) ? threadIdx.x : (128 + c);
    float v = red[0][off]+red[1][off]+red[2][off]+red[3][off];
    atomicAdd(&st[(threadIdx.x<64)? c : 64+c], v);
  }
}

// ---------------- bn6+relu + 2x2 pool pad 1 (7 -> 4); bn6 coef per-thread; y6 -> p6b bf16 ----------------
__global__ __launch_bounds__(256) void k_pool6(const float* __restrict__ y,
                                               const float* __restrict__ stin,
                                               const float* __restrict__ g6, const float* __restrict__ b6,
                                               unsigned short* __restrict__ p6b){
  int idx = blockIdx.x*256 + threadIdx.x;       // NB*16*64 exact
  int oc = idx & 63; int t2 = idx >> 6;
  int xo = t2 & 3;  int yo = (t2>>2) & 3;  int b = t2 >> 4;
  const float invN = 1.f/100352.f;
  float mu = stin[oc]*invN;
  float var = stin[64+oc]*invN - mu*mu;
  float a = g6[oc]*rsqrtf(var + 1e-5f);
  float bo = b6[oc] - mu*a;
  const float* src = y + (size_t)b*3136;
  float mx = -1e30f;
  #pragma unroll
  for (int dy=0;dy<2;dy++){
    int iy = yo*2 - 1 + dy;
    if (iy < 0 || iy >= 7) continue;
    #pragma unroll
    for (int dx=0;dx<2;dx++){
      int ix = xo*2 - 1 + dx;
      if (ix < 0 || ix >= 7) continue;
      mx = fmaxf(mx, src[(iy*7+ix)*64 + oc]*a + bo);
    }
  }
  p6b[(size_t)b*1024 + (yo*4 + xo)*64 + oc] = f2bf(fmaxf(mx, 0.f));
}

// ---------------- conv7 as GEMM: M=2048 (batch), N=256 (pos25*10+o), K=1024; partial max per N-block ----------------
__global__ __launch_bounds__(256) void k_gemm7(const unsigned short* __restrict__ A,   // [2048][1024] bf16
                                               const unsigned short* __restrict__ Bl,  // [256][1024] bf16
                                               float* __restrict__ part){              // [2048][4][10]
  __shared__ float Lw[4][16*65];
  int wid = threadIdx.x>>6, lane = threadIdx.x&63;
  int quad = lane>>4, m = lane&15;
  int blkm = blockIdx.x >> 2, blkn = blockIdx.x & 3;   // grid 128
  int rowb = blkm*64 + wid*16 + m;
  const unsigned short* Arow = A + (size_t)rowb*1024;
  f32x4 acc[4];
  #pragma unroll
  for (int nt=0; nt<4; nt++) acc[nt] = (f32x4){0.f,0.f,0.f,0.f};
  for (int kc=0; kc<32; kc++){
    bf16x8 Af = *(const bf16x8*)(Arow + kc*32 + quad*8);
    #pragma unroll
    for (int nt=0; nt<4; nt++){
      bf16x8 Bf = *(const bf16x8*)(Bl + (size_t)(blkn*64 + nt*16 + m)*1024 + kc*32 + quad*8);
      acc[nt] = __builtin_amdgcn_mfma_f32_16x16x32_bf16(Af, Bf, acc[nt], 0, 0, 0);
    }
  }
  float* Lp = &Lw[wid][0];
  #pragma unroll
  for (int nt=0; nt<4; nt++)
    #pragma unroll
    for (int r=0; r<4; r++)
      Lp[(quad*4+r)*65 + nt*16 + m] = acc[nt][r];
  __syncthreads();
  for (int i=lane; i<160; i+=64){
    int br = i/10, o = i - 10*(i/10);
    int c0 = ((o - blkn*64) % 10 + 10) % 10;
    float mx = -1e30f;
    for (int c=c0; c<64; c+=10){
      if (blkn*64 + c < 250) mx = fmaxf(mx, Lp[br*65 + c]);
    }
    part[((size_t)(blkm*64 + wid*16 + br)*4 + blkn)*10 + o] = mx;
  }
}

// ---------------- logits: max over 4 N-block partials + bias; nms write ----------------
__global__ __launch_bounds__(256) void k_logits(const float* __restrict__ part,
                                                const float* __restrict__ bias,
                                                const float* __restrict__ nmsa,
                                                float* __restrict__ out){
  int idx = blockIdx.x*256 + threadIdx.x;       // 20480 exact (80 blocks)
  int b = idx/10, o = idx - 10*(idx/10);
  const float* p = part + (size_t)b*40 + o;
  float mx = fmaxf(fmaxf(p[0], p[10]), fmaxf(p[20], p[30]));
  out[idx] = mx + bias[o];
  if (blockIdx.x == 0 && threadIdx.x == 0) out[20480] = nmsa[0] * (1.f/12845056.f);
}

extern "C" void kernel_launch(void* const* d_in, const int* in_sizes, int n_in,
                              void* d_out, int out_size, void* d_ws, size_t ws_size,
                              hipStream_t stream){
  const float* x  = (const float*)d_in[0];
  const float* w1 = (const float*)d_in[1];
  const float* w2 = (const float*)d_in[2];
  const float* w3 = (const float*)d_in[3];
  const float* w4 = (const float*)d_in[4];
  const float* w5 = (const float*)d_in[5];
  const float* w6 = (const float*)d_in[6];
  const float* w7 = (const float*)d_in[7];
  const float* g1 = (const float*)d_in[8];
  const float* b1 = (const float*)d_in[9];
  const float* g2 = (const float*)d_in[10];
  const float* b2 = (const float*)d_in[11];
  const float* g3 = (const float*)d_in[12];
  const float* b3 = (const float*)d_in[13];
  const float* g4 = (const float*)d_in[14];
  const float* b4 = (const float*)d_in[15];
  const float* g5 = (const float*)d_in[16];
  const float* b5 = (const float*)d_in[17];
  const float* g6 = (const float*)d_in[18];
  const float* b6 = (const float*)d_in[19];
  const float* b7 = (const float*)d_in[20];
  float* out = (float*)d_out;
  float* W = (float*)d_ws;

  // arena (float units)
  float* p2p  = W + 15728640;          //  8,388,608  (2048*16*256)
  float* y3p  = W + 24117248;          // 16,777,216  (2048*32*256)
  float* p4   = W + 0;                 //  3,211,264  (2048*49*32)
  float* y5   = W + 3407872;           //  6,422,528  (2048*49*64)
  float* y6   = W + 10223616;          //  6,422,528
  unsigned short* p6b = (unsigned short*)(W + 16646144); // 2048*1024 bf16
  unsigned short* wb5 = (unsigned short*)(W + 40894464);  // 9*64*32 bf16
  unsigned short* wb6 = (unsigned short*)(W + 40912896);  // 9*64*64 bf16
  unsigned short* wb4 = (unsigned short*)(W + 40931328);  // 9*32*32 bf16
  float* st   = W + 40949760;          //  2,048
  unsigned short* Bl = (unsigned short*)(W + 40951808);   // 256*1024 bf16
  float* part = W + 41082880;          //  81,920 (2048*4*10)
  unsigned short* B2 = (unsigned short*)(W + 41164800);   // 5*16*32 bf16 (1280 floats)
  unsigned short* B3 = (unsigned short*)(W + 41166080);   // 5*32*32 bf16 (2560 floats)

  float* nmsa = st + 1536;

  k_init<<<283,256,0,stream>>>(w2, w3, w4, w5, w6, B2, B3, wb4, wb5, wb6, st);
  k_init7<<<1024,256,0,stream>>>(w7, Bl);

  k_stats1<<<512,256,0,stream>>>(x, w1, st + 0*128);

  k_conv2m<<<2048,256,0,stream>>>(x, w1, B2, st + 0*128, g1, b1, p2p, st + 1*128);

  k_conv3m<<<2048,256,0,stream>>>(p2p, B3, st + 1*128, g2, b2, y3p, st + 2*128);

  k_conv4m<<<2048,256,0,stream>>>(y3p, wb4, st + 2*128, g3, b3, p4, st + 3*128, nmsa);

  k_conv56m<32><<<512,256,0,stream>>>(p4, wb5, st + 3*128, g4, b4, 1.f/401408.f, y5, st + 4*128);

  k_conv56m<64><<<512,256,0,stream>>>(y5, wb6, st + 4*128, g5, b5, 1.f/100352.f, y6, st + 5*128);

  k_pool6<<<8192,256,0,stream>>>(y6, st + 5*128, g6, b6, p6b);

  k_gemm7<<<128,256,0,stream>>>(p6b, Bl, part);
  k_logits<<<80,256,0,stream>>>(part, b7, nmsa, out);
}

// Round 20
// 366.924 us; speedup vs baseline: 1.0236x; 1.0236x over previous
//
#include <hip/hip_runtime.h>

static constexpr int NB = 2048;
static constexpr float SENT = -1e30f;

typedef __attribute__((ext_vector_type(8))) short bf16x8;
typedef __attribute__((ext_vector_type(4))) float f32x4;

// rotated-3x3 tap permutation: weight tap k of rotation r lands at patch position DST[r][k]
static constexpr int DST[8][9] = {
  {8,7,6,5,4,3,2,1,0},
  {5,8,7,2,4,6,1,0,3},
  {2,5,8,1,4,7,0,3,6},
  {1,2,5,0,4,8,3,6,7},
  {0,1,2,3,4,5,6,7,8},
  {3,0,1,6,4,2,7,8,5},
  {6,3,0,7,4,1,8,5,2},
  {7,6,3,8,4,0,5,2,1},
};

__device__ __forceinline__ unsigned short f2bf(float f){
  unsigned int u = __float_as_uint(f);
  u += 0x7fffu + ((u>>16)&1u);          // RNE
  return (unsigned short)(u>>16);
}

// border cell index (16x16 plane) for border id t<60
__device__ __forceinline__ int border_cell(int t){
  if (t<16) return t;
  if (t<32) return 240 + (t-16);
  if (t<46) return (t-31)*16;
  return (t-45)*16 + 15;
}

// ---------------- pre: weight packs (blocks 0..282) + conv7 B (283..1306) + bn1 stats (1307..1818) ----------------
__global__ __launch_bounds__(256) void k_pre(const float* __restrict__ x, const float* __restrict__ w1,
                                             const float* __restrict__ w2, const float* __restrict__ w3,
                                             const float* __restrict__ w4,
                                             const float* __restrict__ w5, const float* __restrict__ w6,
                                             const float* __restrict__ w7,
                                             unsigned short* __restrict__ B2,
                                             unsigned short* __restrict__ B3,
                                             unsigned short* __restrict__ wb4,
                                             unsigned short* __restrict__ wb5, unsigned short* __restrict__ wb6,
                                             unsigned short* __restrict__ Bl,
                                             float* __restrict__ st){
  int blk = blockIdx.x;
  if (blk < 283){
    int i = blk*256 + threadIdx.x;
    if (i < 18432){                                  // 9*64*32
      int tap = i/2048, rem = i%2048, oc = rem/32, ci = rem%32;
      wb5[i] = f2bf(w5[(oc*32+ci)*9 + tap]);
    } else if (i < 55296){                           // + 9*64*64
      int j = i - 18432;
      int tap = j/4096, rem = j%4096, oc = rem/64, ci = rem%64;
      wb6[j] = f2bf(w6[(oc*64+ci)*9 + tap]);
    } else if (i < 64512){                           // + 9*32*32
      int j = i - 55296;
      int tap = j/1024, rem = j%1024, oc = rem/32, ci = rem%32;
      wb4[j] = f2bf(w4[(oc*32+ci)*9 + tap]);
    } else if (i < 67072){                           // + conv2 tap-pair pack [5][16][32]
      int j = i - 64512;
      int c = j >> 9;
      int rem = j & 511;
      int o = rem >> 5, k = rem & 31;
      int tap = c*2 + (k>>4);
      int ci = k & 15;
      unsigned short v = 0;
      if (tap <= 8){
        int rot = o>>1, u = o&1;
        int bb = ci>>1, ui = ci&1;
        int wc = (((bb - rot) & 7)<<1) | ui;
        int kk = 0;
        #pragma unroll
        for (int q=0;q<9;q++) if (DST[rot][q]==tap) kk=q;
        v = f2bf(w2[(u*16+wc)*9 + kk]);
      }
      B2[j] = v;
    } else if (i < 72192){                           // + conv3 tap-pair pack [5][32][32]
      int j = i - 67072;
      int c = j >> 10;
      int rem = j & 1023;
      int o = rem >> 5, k = rem & 31;
      int tap = c*2 + (k>>4);
      int ci = k & 15;
      unsigned short v = 0;
      if (tap <= 8){
        int rot = o>>2, uh = (o>>1)&1, ul = o&1;
        int bb = ci>>1, ui = ci&1;
        int wc = (((bb - rot) & 7)<<1) | ui;
        int kk = 0;
        #pragma unroll
        for (int q=0;q<9;q++) if (DST[rot][q]==tap) kk=q;
        v = f2bf(w3[uh*288 + (ul*16+wc)*9 + kk]);
      }
      B3[j] = v;
    }
    return;
  }
  if (blk < 1307){
    int i = (blk-283)*256 + threadIdx.x;             // 262144 exact
    int n = i>>10, k = i&1023;
    int pos16 = k>>6, ci = k&63;
    int r = pos16>>2, c = pos16&3;
    unsigned short v = 0;
    if (n < 250){
      int pos = n/10, o = n - 10*(n/10);
      int py = pos/5, px = pos - 5*(pos/5);
      int ky = r - py + 2, kx = c - px + 2;
      if (ky>=0 && ky<4 && kx>=0 && kx<4) v = f2bf(w7[(o*64+ci)*16 + ky*4 + kx]);
    }
    Bl[i] = v;
    return;
  }
  // ---- bn1 stats over y1 = rotconv1(x) ----
  __shared__ float wp[192];
  __shared__ float red[4][32];
  for (int i=threadIdx.x; i<144; i+=256){
    int rot = i/18, rem = i-rot*18, u = rem/9, k = rem-u*9;
    wp[(rot*2+u)*12 + DST[rot][k]] = w1[u*9+k];
  }
  __syncthreads();
  float s[16], s2[16];
  #pragma unroll
  for (int o=0;o<16;o++){ s[o]=0.f; s2[o]=0.f; }
  for (int idx = (blk-1307)*256 + threadIdx.x; idx < NB*784; idx += 512*256){
    int b = idx/784, pix = idx-b*784;
    int py = pix/28, px = pix-py*28;
    const float* xb = x + (size_t)b*784;
    float tap[9];
    #pragma unroll
    for (int d=0; d<9; d++){
      int dy = d/3-1, dx = d%3-1;
      int yy = py+dy, xx = px+dx;
      tap[d] = (yy>=0 && yy<28 && xx>=0 && xx<28) ? xb[yy*28+xx] : 0.f;
    }
    #pragma unroll
    for (int ci=0; ci<16; ci++){
      float y = 0.f;
      #pragma unroll
      for (int d=0; d<9; d++) y += wp[ci*12+d]*tap[d];
      s[ci] += y; s2[ci] += y*y;
    }
  }
  int wid = threadIdx.x>>6;
  #pragma unroll
  for (int o=0;o<16;o++){
    float a = s[o], b2 = s2[o];
    #pragma unroll
    for (int off=32; off; off>>=1){ a += __shfl_down(a,off); b2 += __shfl_down(b2,off); }
    if ((threadIdx.x&63)==0){ red[wid][o] = a; red[wid][16+o] = b2; }
  }
  __syncthreads();
  if (threadIdx.x < 32){
    float v = red[0][threadIdx.x]+red[1][threadIdx.x]+red[2][threadIdx.x]+red[3][threadIdx.x];
    int c = threadIdx.x & 15;
    atomicAdd(&st[(threadIdx.x<16)? c : 64+c], v);
  }
}

// ---------------- conv2 MFMA: recompute y1 from x in-block; bn1 coef computed in-block from sums ----------------
// LDS union inside smemf: Ls bf16 [960][16] = [0,7680) fl | xs [7680,8640) | wp [8640,8832) ; out = [0,13328).
__global__ __launch_bounds__(256, 2) void k_conv2m(const float* __restrict__ x,
                                                   const float* __restrict__ w1,
                                                   const unsigned short* __restrict__ B2,  // [5][16][32] bf16
                                                   const float* __restrict__ stin,   // bn1 sums
                                                   const float* __restrict__ g1, const float* __restrict__ b1,
                                                   float* __restrict__ p2p,
                                                   float* __restrict__ st){
  __shared__ float smemf[13328];
  __shared__ float ca[16], cb[16];
  __shared__ float red[4][32];
  unsigned short* Ls = (unsigned short*)smemf;   // floats [0, 7680)
  float* xs = smemf + 7680;                      // floats [7680, 8640)
  float* wp = smemf + 8640;                      // floats [8640, 8832)
  float* out = smemf;
  int t = threadIdx.x;
  int wid = t>>6, lane = t&63;
  int quad = lane>>4, m = lane&15;
  for (int i=t; i<144; i+=256){
    int rot = i/18, rem = i-rot*18, u = rem/9, k = rem-u*9;
    wp[(rot*2+u)*12 + DST[rot][k]] = w1[u*9+k];
  }
  if (t < 16){
    const float invN = 1.f/1605632.f;
    float mu = stin[t]*invN;
    float var = stin[64+t]*invN - mu*mu;
    float a = g1[t&1]*rsqrtf(var + 1e-5f);
    ca[t] = a; cb[t] = b1[t&1] - mu*a;
  }
  int b = blockIdx.x;
  for (int i=t; i<960; i+=256){
    int r = i>>5, c = i&31;
    int iy = r-1, ix = c-1;
    xs[i] = (iy>=0 && iy<28 && ix>=0 && ix<28) ? x[(size_t)b*784 + iy*28 + ix] : 0.f;
  }
  for (int i=t; i<3840; i+=256) ((unsigned long long*)Ls)[i] = 0ULL;
  __syncthreads();
  for (int i=t; i<784; i+=256){
    int py = i/28, px = i - 28*(i/28);
    float tap[9];
    #pragma unroll
    for (int d=0; d<9; d++) tap[d] = xs[(py + d/3)*32 + px + d%3];
    unsigned long long pk[4];
    #pragma unroll
    for (int q=0; q<4; q++){
      unsigned long long p = 0;
      #pragma unroll
      for (int j=0; j<4; j++){
        int ci = q*4 + j;
        float y = 0.f;
        #pragma unroll
        for (int d=0; d<9; d++) y += wp[ci*12+d]*tap[d];
        float rv = fmaxf(y*ca[ci] + cb[ci], 0.f);
        p |= ((unsigned long long)f2bf(rv)) << (16*j);
      }
      pk[q] = p;
    }
    int cell = (py+1)*32 + px + 1;
    unsigned long long* dstp = (unsigned long long*)(Ls + cell*16);
    dstp[0]=pk[0]; dstp[1]=pk[1]; dstp[2]=pk[2]; dstp[3]=pk[3];
  }
  __syncthreads();
  f32x4 acc[13];
  #pragma unroll
  for (int j=0;j<13;j++) acc[j] = (f32x4){0.f,0.f,0.f,0.f};
  #pragma unroll
  for (int c=0;c<5;c++){
    int tapA = 2*c, tapB = (2*c+1 < 9) ? 2*c+1 : 8;
    int dyA = tapA/3, dxA = tapA - 3*(tapA/3);
    int dyB = tapB/3, dxB = tapB - 3*(tapB/3);
    bf16x8 Bf = *(const bf16x8*)(B2 + (c*16 + m)*32 + quad*8);
    #pragma unroll
    for (int j=0;j<13;j++){
      int mt = wid + 4*j;
      if (mt >= 49) continue;
      int pos = mt*16 + m;
      int py = pos/28, px = pos - py*28;
      int pix = (quad < 2) ? ((py+dyA)*32 + px+dxA) : ((py+dyB)*32 + px+dxB);
      bf16x8 Af = *(const bf16x8*)(Ls + pix*16 + (quad&1)*8);
      acc[j] = __builtin_amdgcn_mfma_f32_16x16x32_bf16(Af, Bf, acc[j], 0, 0, 0);
    }
  }
  __syncthreads();
  float s = 0.f, sq = 0.f;
  #pragma unroll
  for (int j=0;j<13;j++){
    int mt = wid + 4*j;
    if (mt >= 49) continue;
    #pragma unroll
    for (int r=0;r<4;r++){
      int pos = mt*16 + quad*4 + r;
      float v = acc[j][r];
      out[pos*17 + m] = v;
      s += v; sq += v*v;
    }
  }
  s += __shfl_down(s,32);  s += __shfl_down(s,16);
  sq += __shfl_down(sq,32); sq += __shfl_down(sq,16);
  if (lane < 16){ red[wid][m] = s; red[wid][16+m] = sq; }
  __syncthreads();
  if (t < 32){
    float v = red[0][t]+red[1][t]+red[2][t]+red[3][t];
    int c = t & 15;
    atomicAdd(&st[(t<16)? c : 64+c], v);
  }
  for (int i=t; i<3136; i+=256){
    int cell = i>>4, oc = i&15;
    int yo = cell/14, xo = cell - yo*14;
    const float* o00 = out + ((yo*2)*28 + xo*2)*17 + oc;
    float mx = fmaxf(fmaxf(o00[0], o00[17]), fmaxf(o00[476], o00[493]));
    p2p[((size_t)b*16+oc)*256 + (yo+1)*16 + xo + 1] = mx;
  }
  for (int i=t; i<960; i+=256){
    int bc = border_cell(i>>4), oc = i&15;
    p2p[((size_t)b*16+oc)*256 + bc] = SENT;
  }
}

// ---------------- conv3 MFMA: 16->32 rotated over 14x14, bn2 coef in-block, stats, padded y3 out ----------------
__global__ __launch_bounds__(256, 2) void k_conv3m(const float* __restrict__ p2p,
                                                   const unsigned short* __restrict__ B3,  // [5][32][32] bf16
                                                   const float* __restrict__ stin,
                                                   const float* __restrict__ g2, const float* __restrict__ b2,
                                                   float* __restrict__ y3p,
                                                   float* __restrict__ st){
  __shared__ float smemf[6468];
  __shared__ float ca[16], cb[16];
  __shared__ float red[4][64];
  unsigned short* Ls = (unsigned short*)smemf;
  float* out = smemf;
  int t = threadIdx.x;
  int wid = t>>6, lane = t&63;
  int quad = lane>>4, m = lane&15;
  if (t < 16){
    const float invN = 1.f/1605632.f;
    float mu = stin[t]*invN;
    float var = stin[64+t]*invN - mu*mu;
    float a = g2[t&1]*rsqrtf(var + 1e-5f);
    ca[t] = a; cb[t] = b2[t&1] - mu*a;
  }
  __syncthreads();
  int b = blockIdx.x;
  const float* sb = p2p + (size_t)b*4096;
  #pragma unroll
  for (int it=0; it<4; it++){
    unsigned long long pk = 0;
    #pragma unroll
    for (int j=0;j<4;j++){
      int ci = it*4 + j;
      float v = fmaxf(sb[ci*256 + t]*ca[ci] + cb[ci], 0.f);
      pk |= ((unsigned long long)f2bf(v)) << (16*j);
    }
    *(unsigned long long*)(Ls + t*16 + it*4) = pk;
  }
  __syncthreads();
  int py[4], px[4]; bool vt[4];
  #pragma unroll
  for (int j=0;j<4;j++){
    int mt = wid + 4*j;
    int pos = mt*16 + m;
    vt[j] = (mt <= 12);
    if (pos >= 196) pos = 0;
    py[j] = pos/14; px[j] = pos%14;
  }
  f32x4 acc[4][2];
  #pragma unroll
  for (int j=0;j<4;j++){ acc[j][0] = (f32x4){0,0,0,0}; acc[j][1] = (f32x4){0,0,0,0}; }
  #pragma unroll
  for (int c=0;c<5;c++){
    int tapA = 2*c, tapB = (2*c+1 < 9) ? 2*c+1 : 8;
    int dyA = tapA/3, dxA = tapA - 3*(tapA/3);
    int dyB = tapB/3, dxB = tapB - 3*(tapB/3);
    bf16x8 Bf[2];
    #pragma unroll
    for (int nt=0; nt<2; nt++)
      Bf[nt] = *(const bf16x8*)(B3 + (c*32 + nt*16 + m)*32 + quad*8);
    bf16x8 Af[4];
    #pragma unroll
    for (int j=0;j<4;j++){
      int pix = (quad < 2) ? ((py[j]+dyA)*16 + px[j]+dxA) : ((py[j]+dyB)*16 + px[j]+dxB);
      Af[j] = *(const bf16x8*)(Ls + pix*16 + (quad&1)*8);
    }
    #pragma unroll
    for (int j=0;j<4;j++){
      if (!vt[j]) continue;
      acc[j][0] = __builtin_amdgcn_mfma_f32_16x16x32_bf16(Af[j], Bf[0], acc[j][0], 0, 0, 0);
      acc[j][1] = __builtin_amdgcn_mfma_f32_16x16x32_bf16(Af[j], Bf[1], acc[j][1], 0, 0, 0);
    }
  }
  __syncthreads();   // done reading Ls; reuse as out
  float s0=0.f,sq0=0.f,s1=0.f,sq1=0.f;
  #pragma unroll
  for (int j=0;j<4;j++){
    if (!vt[j]) continue;
    int mt = wid + 4*j;
    #pragma unroll
    for (int r=0;r<4;r++){
      int pos = mt*16 + quad*4 + r;
      if (pos < 196){
        float v0 = acc[j][0][r], v1 = acc[j][1][r];
        out[pos*33 + m]      = v0;
        out[pos*33 + 16 + m] = v1;
        s0 += v0; sq0 += v0*v0; s1 += v1; sq1 += v1*v1;
      }
    }
  }
  s0 += __shfl_down(s0,32); s0 += __shfl_down(s0,16);
  sq0 += __shfl_down(sq0,32); sq0 += __shfl_down(sq0,16);
  s1 += __shfl_down(s1,32); s1 += __shfl_down(s1,16);
  sq1 += __shfl_down(sq1,32); sq1 += __shfl_down(sq1,16);
  if (lane < 16){
    red[wid][m]      = s0;  red[wid][32+m]      = sq0;
    red[wid][16+m]   = s1;  red[wid][32+16+m]   = sq1;
  }
  __syncthreads();
  if (t < 64){
    float v = red[0][t]+red[1][t]+red[2][t]+red[3][t];
    int c = t & 31;
    atomicAdd(&st[(t<32)? c : 64+c], v);
  }
  for (int i=t; i<6272; i+=256){
    int oc = i/196, pos = i - oc*196;
    int py2 = pos/14, px2 = pos - py2*14;
    y3p[(size_t)b*8192 + oc*256 + (py2+1)*16 + px2 + 1] = out[pos*33 + oc];
  }
  for (int i=t; i<1920; i+=256){
    int bc = border_cell(i>>5), oc = i&31;
    y3p[(size_t)b*8192 + oc*256 + bc] = SENT;
  }
}

// ---------------- conv4 MFMA: 32->32 over 14x14, bn3 coef in-block, FUSED NMS, stats + raw pool -> p4 ----------------
__global__ __launch_bounds__(256, 2) void k_conv4m(const float* __restrict__ y3p,
                                                   const unsigned short* __restrict__ wb4, // [9][32][32] bf16
                                                   const float* __restrict__ stin,
                                                   const float* __restrict__ g3, const float* __restrict__ b3,
                                                   float* __restrict__ p4,
                                                   float* __restrict__ st,
                                                   float* __restrict__ nmsa){
  __shared__ float smemf[6468];
  __shared__ float ca[32], cb[32];
  __shared__ float red[4][64];
  __shared__ float nred[4];
  unsigned short* L = (unsigned short*)smemf;
  float* out = smemf;
  int t = threadIdx.x;
  int wid = t>>6, lane = t&63;
  int quad = lane>>4, m = lane&15;
  if (t < 32){
    const float invN = 1.f/401408.f;
    float mu = stin[t]*invN;
    float var = stin[64+t]*invN - mu*mu;
    float a = g3[t&3]*rsqrtf(var + 1e-5f);
    ca[t] = a; cb[t] = b3[t&3] - mu*a;
  }
  __syncthreads();
  int b = blockIdx.x;
  const float* sb = y3p + (size_t)b*8192;
  #pragma unroll
  for (int it=0; it<8; it++){
    int cell = t;
    unsigned long long pk = 0;
    #pragma unroll
    for (int j=0;j<4;j++){
      int ci = it*4 + j;
      float v = fmaxf(sb[ci*256 + cell]*ca[ci] + cb[ci], 0.f);
      pk |= ((unsigned long long)f2bf(v)) << (16*j);
    }
    *(unsigned long long*)(L + cell*40 + it*4) = pk;
  }
  __syncthreads();
  float nloc = 0.f;
  for (int i=t; i<784; i+=256){
    int hw = i>>2, c4 = i&3;
    int cell = (hw/14 + 1)*16 + hw%14 + 1;
    const unsigned short* g = L + cell*40 + c4*8;
    float v[8]; float vmax = -1e30f;
    #pragma unroll
    for (int r=0;r<8;r++){
      v[r] = __uint_as_float((unsigned int)g[r] << 16);
      vmax = fmaxf(vmax, v[r]);
    }
    #pragma unroll
    for (int r=0;r<8;r++) nloc += (v[r] != vmax) ? v[r] : 0.f;
  }
  #pragma unroll
  for (int off=32; off; off>>=1) nloc += __shfl_down(nloc, off);
  if (lane == 0) nred[wid] = nloc;
  int py[4], px[4]; bool vt[4];
  #pragma unroll
  for (int j=0;j<4;j++){
    int mt = wid + 4*j;
    int pos = mt*16 + m;
    vt[j] = (mt <= 12);
    if (pos >= 196) pos = 0;
    py[j] = pos/14; px[j] = pos%14;
  }
  f32x4 acc[4][2];
  #pragma unroll
  for (int j=0;j<4;j++){ acc[j][0] = (f32x4){0,0,0,0}; acc[j][1] = (f32x4){0,0,0,0}; }
  for (int tap=0; tap<9; tap++){
    int dy = tap/3, dx = tap - dy*3;
    bf16x8 Bf[2];
    #pragma unroll
    for (int nt=0; nt<2; nt++)
      Bf[nt] = *(const bf16x8*)(wb4 + (tap*32 + nt*16 + m)*32 + quad*8);
    bf16x8 Af[4];
    #pragma unroll
    for (int j=0;j<4;j++)
      Af[j] = *(const bf16x8*)(L + ((py[j]+dy)*16 + px[j]+dx)*40 + quad*8);
    #pragma unroll
    for (int j=0;j<4;j++){
      if (!vt[j]) continue;
      acc[j][0] = __builtin_amdgcn_mfma_f32_16x16x32_bf16(Af[j], Bf[0], acc[j][0], 0, 0, 0);
      acc[j][1] = __builtin_amdgcn_mfma_f32_16x16x32_bf16(Af[j], Bf[1], acc[j][1], 0, 0, 0);
    }
  }
  __syncthreads();
  if (t == 0) atomicAdd(nmsa, nred[0]+nred[1]+nred[2]+nred[3]);
  float s0=0.f,sq0=0.f,s1=0.f,sq1=0.f;
  #pragma unroll
  for (int j=0;j<4;j++){
    if (!vt[j]) continue;
    int mt = wid + 4*j;
    #pragma unroll
    for (int r=0;r<4;r++){
      int pos = mt*16 + quad*4 + r;
      if (pos < 196){
        float v0 = acc[j][0][r], v1 = acc[j][1][r];
        out[pos*33 + m]      = v0;
        out[pos*33 + 16 + m] = v1;
        s0 += v0; sq0 += v0*v0; s1 += v1; sq1 += v1*v1;
      }
    }
  }
  s0 += __shfl_down(s0,32); s0 += __shfl_down(s0,16);
  sq0 += __shfl_down(sq0,32); sq0 += __shfl_down(sq0,16);
  s1 += __shfl_down(s1,32); s1 += __shfl_down(s1,16);
  sq1 += __shfl_down(sq1,32); sq1 += __shfl_down(sq1,16);
  if (lane < 16){
    red[wid][m]      = s0;  red[wid][32+m]      = sq0;
    red[wid][16+m]   = s1;  red[wid][32+16+m]   = sq1;
  }
  __syncthreads();
  if (t < 64){
    float v = red[0][t]+red[1][t]+red[2][t]+red[3][t];
    int c = t & 31;
    atomicAdd(&st[(t<32)? c : 64+c], v);
  }
  for (int i=t; i<1568; i+=256){
    int cell = i>>5, oc = i&31;
    int yo = cell/7, xo = cell - yo*7;
    const float* o00 = out + ((yo*2)*14 + xo*2)*33 + oc;
    float mx = fmaxf(fmaxf(o00[0], o00[33]), fmaxf(o00[14*33], o00[15*33]));
    p4[((size_t)b*49 + cell)*32 + oc] = mx;
  }
}

// ---------------- conv5/conv6 MFMA: CI->64, per-wave batch, bn coef in-block, shift-GEMM over 9 taps ----------------
template<int CI>
__global__ __launch_bounds__(256, 2) void k_conv56m(const float* __restrict__ src,
                                                    const unsigned short* __restrict__ wb,  // [9][64][CI] bf16
                                                    const float* __restrict__ stin,
                                                    const float* __restrict__ g, const float* __restrict__ be,
                                                    float invN,
                                                    float* __restrict__ dst,
                                                    float* __restrict__ st){
  constexpr int CIP = CI + 8;
  constexpr int KC = CI/32;
  __shared__ unsigned short lin[4][81*CIP];
  __shared__ float red[4][256];
  __shared__ float ca[CI], cb[CI];
  int wid = threadIdx.x>>6, lane = threadIdx.x&63;
  int quad = lane>>4, m = lane&15;
  unsigned short* L = lin[wid];
  if (threadIdx.x < CI){
    int i = threadIdx.x;
    float mu = stin[i]*invN;
    float var = stin[64+i]*invN - mu*mu;
    float a = g[i]*rsqrtf(var + 1e-5f);
    ca[i] = a; cb[i] = be[i] - mu*a;
  }
  for (int i = lane; i < 81*CIP/4; i += 64) ((unsigned long long*)L)[i] = 0ULL;
  __syncthreads();
  int b = blockIdx.x*4 + wid;
  const float* sb = src + (size_t)b*49*CI;
  for (int i = lane; i < 49*CI/4; i += 64){
    int pos = i/(CI/4), cig = i - pos*(CI/4);
    float4 v = *(const float4*)(sb + pos*CI + cig*4);
    float r0 = fmaxf(v.x*ca[cig*4]  +cb[cig*4],   0.f);
    float r1 = fmaxf(v.y*ca[cig*4+1]+cb[cig*4+1], 0.f);
    float r2 = fmaxf(v.z*ca[cig*4+2]+cb[cig*4+2], 0.f);
    float r3 = fmaxf(v.w*ca[cig*4+3]+cb[cig*4+3], 0.f);
    int pos9 = (pos/7 + 1)*9 + pos%7 + 1;
    unsigned long long pk = (unsigned long long)f2bf(r0)
                          | ((unsigned long long)f2bf(r1)<<16)
                          | ((unsigned long long)f2bf(r2)<<32)
                          | ((unsigned long long)f2bf(r3)<<48);
    *(unsigned long long*)(L + pos9*CIP + cig*4) = pk;
  }
  __syncthreads();
  int py[4], px[4];
  #pragma unroll
  for (int mt=0; mt<4; mt++){
    int pos = mt*16 + m;
    if (pos < 49){ py[mt] = pos/7; px[mt] = pos%7; }
    else { py[mt] = 0; px[mt] = 0; }
  }
  f32x4 acc[4][4];
  #pragma unroll
  for (int nt=0; nt<4; nt++)
    #pragma unroll
    for (int mt=0; mt<4; mt++) acc[nt][mt] = (f32x4){0.f,0.f,0.f,0.f};

  for (int tap=0; tap<9; tap++){
    int dy = tap/3, dx = tap - dy*3;
    int o9[4];
    #pragma unroll
    for (int mt=0; mt<4; mt++) o9[mt] = ((py[mt]+dy)*9 + px[mt]+dx)*CIP;
    #pragma unroll
    for (int kc=0; kc<KC; kc++){
      int ko = kc*32 + quad*8;
      bf16x8 Bf[4], Af[4];
      #pragma unroll
      for (int nt=0; nt<4; nt++)
        Bf[nt] = *(const bf16x8*)(wb + (tap*64 + nt*16 + m)*CI + ko);
      #pragma unroll
      for (int mt=0; mt<4; mt++)
        Af[mt] = *(const bf16x8*)(L + o9[mt] + ko);
      #pragma unroll
      for (int nt=0; nt<4; nt++)
        #pragma unroll
        for (int mt=0; mt<4; mt++)
          acc[nt][mt] = __builtin_amdgcn_mfma_f32_16x16x32_bf16(Af[mt], Bf[nt], acc[nt][mt], 0, 0, 0);
    }
  }
  float* db = dst + (size_t)b*49*64;
  float snt[4], sqnt[4];
  #pragma unroll
  for (int nt=0; nt<4; nt++){
    float s = 0.f, sq = 0.f;
    #pragma unroll
    for (int mt=0; mt<4; mt++){
      #pragma unroll
      for (int r=0; r<4; r++){
        int pos = mt*16 + quad*4 + r;
        if (pos < 49){
          float v = acc[nt][mt][r];
          db[pos*64 + nt*16 + m] = v;
          s += v; sq += v*v;
        }
      }
    }
    s += __shfl_down(s, 32);  s += __shfl_down(s, 16);
    sq += __shfl_down(sq, 32); sq += __shfl_down(sq, 16);
    snt[nt] = s; sqnt[nt] = sq;
  }
  if (lane < 16){
    #pragma unroll
    for (int nt=0; nt<4; nt++){
      red[wid][nt*16 + lane] = snt[nt];
      red[wid][128 + nt*16 + lane] = sqnt[nt];
    }
  }
  __syncthreads();
  if (threadIdx.x < 128){
    int c = threadIdx.x & 63;
    int off = (threadIdx.x < 64) ? threadIdx.x : (128 + c);
    float v = red[0][off]+red[1][off]+red[2][off]+red[3][off];
    atomicAdd(&st[(threadIdx.x<64)? c : 64+c], v);
  }
}

// ---------------- bn6+relu + 2x2 pool pad 1 (7 -> 4); bn6 coef per-thread; y6 -> p6b bf16 ----------------
__global__ __launch_bounds__(256) void k_pool6(const float* __restrict__ y,
                                               const float* __restrict__ stin,
                                               const float* __restrict__ g6, const float* __restrict__ b6,
                                               unsigned short* __restrict__ p6b){
  int idx = blockIdx.x*256 + threadIdx.x;       // NB*16*64 exact
  int oc = idx & 63; int t2 = idx >> 6;
  int xo = t2 & 3;  int yo = (t2>>2) & 3;  int b = t2 >> 4;
  const float invN = 1.f/100352.f;
  float mu = stin[oc]*invN;
  float var = stin[64+oc]*invN - mu*mu;
  float a = g6[oc]*rsqrtf(var + 1e-5f);
  float bo = b6[oc] - mu*a;
  const float* src = y + (size_t)b*3136;
  float mx = -1e30f;
  #pragma unroll
  for (int dy=0;dy<2;dy++){
    int iy = yo*2 - 1 + dy;
    if (iy < 0 || iy >= 7) continue;
    #pragma unroll
    for (int dx=0;dx<2;dx++){
      int ix = xo*2 - 1 + dx;
      if (ix < 0 || ix >= 7) continue;
      mx = fmaxf(mx, src[(iy*7+ix)*64 + oc]*a + bo);
    }
  }
  p6b[(size_t)b*1024 + (yo*4 + xo)*64 + oc] = f2bf(fmaxf(mx, 0.f));
}

// ---------------- conv7 as GEMM: M=2048 (batch), N=256 (pos25*10+o), K=1024; partial max per N-block ----------------
__global__ __launch_bounds__(256) void k_gemm7(const unsigned short* __restrict__ A,   // [2048][1024] bf16
                                               const unsigned short* __restrict__ Bl,  // [256][1024] bf16
                                               float* __restrict__ part){              // [2048][4][10]
  __shared__ float Lw[4][16*65];
  int wid = threadIdx.x>>6, lane = threadIdx.x&63;
  int quad = lane>>4, m = lane&15;
  int blkm = blockIdx.x >> 2, blkn = blockIdx.x & 3;   // grid 128
  int rowb = blkm*64 + wid*16 + m;
  const unsigned short* Arow = A + (size_t)rowb*1024;
  f32x4 acc[4];
  #pragma unroll
  for (int nt=0; nt<4; nt++) acc[nt] = (f32x4){0.f,0.f,0.f,0.f};
  for (int kc=0; kc<32; kc++){
    bf16x8 Af = *(const bf16x8*)(Arow + kc*32 + quad*8);
    #pragma unroll
    for (int nt=0; nt<4; nt++){
      bf16x8 Bf = *(const bf16x8*)(Bl + (size_t)(blkn*64 + nt*16 + m)*1024 + kc*32 + quad*8);
      acc[nt] = __builtin_amdgcn_mfma_f32_16x16x32_bf16(Af, Bf, acc[nt], 0, 0, 0);
    }
  }
  float* Lp = &Lw[wid][0];
  #pragma unroll
  for (int nt=0; nt<4; nt++)
    #pragma unroll
    for (int r=0; r<4; r++)
      Lp[(quad*4+r)*65 + nt*16 + m] = acc[nt][r];
  __syncthreads();
  for (int i=lane; i<160; i+=64){
    int br = i/10, o = i - 10*(i/10);
    int c0 = ((o - blkn*64) % 10 + 10) % 10;
    float mx = -1e30f;
    for (int c=c0; c<64; c+=10){
      if (blkn*64 + c < 250) mx = fmaxf(mx, Lp[br*65 + c]);
    }
    part[((size_t)(blkm*64 + wid*16 + br)*4 + blkn)*10 + o] = mx;
  }
}

// ---------------- logits: max over 4 N-block partials + bias; nms write ----------------
__global__ __launch_bounds__(256) void k_logits(const float* __restrict__ part,
                                                const float* __restrict__ bias,
                                                const float* __restrict__ nmsa,
                                                float* __restrict__ out){
  int idx = blockIdx.x*256 + threadIdx.x;       // 20480 exact (80 blocks)
  int b = idx/10, o = idx - 10*(idx/10);
  const float* p = part + (size_t)b*40 + o;
  float mx = fmaxf(fmaxf(p[0], p[10]), fmaxf(p[20], p[30]));
  out[idx] = mx + bias[o];
  if (blockIdx.x == 0 && threadIdx.x == 0) out[20480] = nmsa[0] * (1.f/12845056.f);
}

extern "C" void kernel_launch(void* const* d_in, const int* in_sizes, int n_in,
                              void* d_out, int out_size, void* d_ws, size_t ws_size,
                              hipStream_t stream){
  const float* x  = (const float*)d_in[0];
  const float* w1 = (const float*)d_in[1];
  const float* w2 = (const float*)d_in[2];
  const float* w3 = (const float*)d_in[3];
  const float* w4 = (const float*)d_in[4];
  const float* w5 = (const float*)d_in[5];
  const float* w6 = (const float*)d_in[6];
  const float* w7 = (const float*)d_in[7];
  const float* g1 = (const float*)d_in[8];
  const float* b1 = (const float*)d_in[9];
  const float* g2 = (const float*)d_in[10];
  const float* b2 = (const float*)d_in[11];
  const float* g3 = (const float*)d_in[12];
  const float* b3 = (const float*)d_in[13];
  const float* g4 = (const float*)d_in[14];
  const float* b4 = (const float*)d_in[15];
  const float* g5 = (const float*)d_in[16];
  const float* b5 = (const float*)d_in[17];
  const float* g6 = (const float*)d_in[18];
  const float* b6 = (const float*)d_in[19];
  const float* b7 = (const float*)d_in[20];
  float* out = (float*)d_out;
  float* W = (float*)d_ws;

  // arena (float units)
  float* p2p  = W + 15728640;          //  8,388,608  (2048*16*256)
  float* y3p  = W + 24117248;          // 16,777,216  (2048*32*256)
  float* p4   = W + 0;                 //  3,211,264  (2048*49*32)
  float* y5   = W + 3407872;           //  6,422,528  (2048*49*64)
  float* y6   = W + 10223616;          //  6,422,528
  unsigned short* p6b = (unsigned short*)(W + 16646144); // 2048*1024 bf16
  unsigned short* wb5 = (unsigned short*)(W + 40894464);  // 9*64*32 bf16
  unsigned short* wb6 = (unsigned short*)(W + 40912896);  // 9*64*64 bf16
  unsigned short* wb4 = (unsigned short*)(W + 40931328);  // 9*32*32 bf16
  float* st   = W + 40949760;          //  2,048
  unsigned short* Bl = (unsigned short*)(W + 40951808);   // 256*1024 bf16
  float* part = W + 41082880;          //  81,920 (2048*4*10)
  unsigned short* B2 = (unsigned short*)(W + 41164800);   // 5*16*32 bf16 (1280 floats)
  unsigned short* B3 = (unsigned short*)(W + 41166080);   // 5*32*32 bf16 (2560 floats)

  float* nmsa = st + 1536;

  hipMemsetAsync(st, 0, 2048*sizeof(float), stream);

  k_pre<<<1819,256,0,stream>>>(x, w1, w2, w3, w4, w5, w6, w7,
                               B2, B3, wb4, wb5, wb6, Bl, st + 0*128);

  k_conv2m<<<2048,256,0,stream>>>(x, w1, B2, st + 0*128, g1, b1, p2p, st + 1*128);

  k_conv3m<<<2048,256,0,stream>>>(p2p, B3, st + 1*128, g2, b2, y3p, st + 2*128);

  k_conv4m<<<2048,256,0,stream>>>(y3p, wb4, st + 2*128, g3, b3, p4, st + 3*128, nmsa);

  k_conv56m<32><<<512,256,0,stream>>>(p4, wb5, st + 3*128, g4, b4, 1.f/401408.f, y5, st + 4*128);

  k_conv56m<64><<<512,256,0,stream>>>(y5, wb6, st + 4*128, g5, b5, 1.f/100352.f, y6, st + 5*128);

  k_pool6<<<8192,256,0,stream>>>(y6, st + 5*128, g6, b6, p6b);

  k_gemm7<<<128,256,0,stream>>>(p6b, Bl, part);
  k_logits<<<80,256,0,stream>>>(part, b7, nmsa, out);
}